// Round 2
// baseline (638.962 us; speedup 1.0000x reference)
//
#include <hip/hip_runtime.h>

// ---------------------------------------------------------------------------
// PAM: out = gamma * softmax((X Wb)(X Wc)^T) (X Wd) + X
// B=4, H=W=64 (N=4096), C=512, CR=64. Inputs/outputs fp32; MFMA in bf16 with
// hi/lo splitting for Q/K accuracy.
// ---------------------------------------------------------------------------

typedef __bf16 bf16_t;
typedef __bf16 bf16x8 __attribute__((ext_vector_type(8)));
typedef float f32x4 __attribute__((ext_vector_type(4)));

#define NN 4096
#define CC 512

// workspace layout, in bf16 elements (total 12976128 el = 25.95 MB)
#define OFF_QH 0u
#define OFF_QL 1048576u
#define OFF_KH 2097152u
#define OFF_KL 3145728u
#define OFF_VT 4194304u            // Vt[b][c][n], 4*512*4096
#define OFF_WBH 12582912u          // Wt_b hi [64][512]
#define OFF_WBL 12615680u
#define OFF_WCH 12648448u
#define OFF_WCL 12681216u
#define OFF_WD  12713984u          // Wt_d [512][512]

static __device__ __forceinline__ f32x4 mfma16(bf16x8 a, bf16x8 b, f32x4 c) {
    return __builtin_amdgcn_mfma_f32_16x16x32_bf16(a, b, c, 0, 0, 0);
}

// --------------------------- K0: weight prep (fp32 -> bf16, transpose) ------
__global__ __launch_bounds__(256) void prep_kernel(const float* __restrict__ Wb,
                                                   const float* __restrict__ Wc,
                                                   const float* __restrict__ Wd,
                                                   bf16_t* __restrict__ ws) {
    int idx = blockIdx.x * 256 + threadIdx.x;
    if (idx < 32768) {                        // Wb [512][64] -> hi/lo [64][512]
        int n = idx >> 9, k = idx & 511;
        float v = Wb[k * 64 + n];
        bf16_t h = (bf16_t)v;
        ws[OFF_WBH + idx] = h;
        ws[OFF_WBL + idx] = (bf16_t)(v - (float)h);
    } else if (idx < 65536) {
        int j = idx - 32768;
        int n = j >> 9, k = j & 511;
        float v = Wc[k * 64 + n];
        bf16_t h = (bf16_t)v;
        ws[OFF_WCH + j] = h;
        ws[OFF_WCL + j] = (bf16_t)(v - (float)h);
    } else if (idx < 65536 + 262144) {        // Wd [512][512] -> [64x8][512]
        int j = idx - 65536;
        int n = j >> 9, k = j & 511;
        ws[OFF_WD + j] = (bf16_t)Wd[k * 512 + n];
    }
}

// --------------------------- K1: fused QKV projection -----------------------
// X[16384,512] (fp32, bf16-converted in-register) times W[512,640].
// nT=0 -> Q (hi/lo out), nT=1 -> K (hi/lo out), nT>=2 -> V stored Vt[b][c][n].
__global__ __launch_bounds__(256) void qkv_kernel(const float* __restrict__ x,
                                                  bf16_t* __restrict__ ws) {
    int nT = blockIdx.x % 10;
    int mt = blockIdx.x / 10;
    int tid = threadIdx.x;
    int w = tid >> 6, lane = tid & 63, quad = lane >> 4, l16 = lane & 15;

    const float* xrow = x + (size_t)(mt * 64 + w * 16 + l16) * 512;

    f32x4 acc[4];
#pragma unroll
    for (int nt = 0; nt < 4; ++nt) acc[nt] = (f32x4){0.f, 0.f, 0.f, 0.f};

    if (nT < 2) {
        // Q/K path: hi/lo split on BOTH X and W -> near-fp32 projection
        const bf16_t* wh = ws + (nT == 0 ? OFF_WBH : OFF_WCH);
        const bf16_t* wl = ws + (nT == 0 ? OFF_WBL : OFF_WCL);
#pragma unroll 2
        for (int ks = 0; ks < 16; ++ks) {
            f32x4 a0 = *(const f32x4*)(xrow + ks * 32 + quad * 8);
            f32x4 a1 = *(const f32x4*)(xrow + ks * 32 + quad * 8 + 4);
            bf16x8 xh, xl;
#pragma unroll
            for (int j = 0; j < 4; ++j) {
                bf16_t h0 = (bf16_t)a0[j];
                bf16_t h1 = (bf16_t)a1[j];
                xh[j] = h0;     xl[j] = (bf16_t)(a0[j] - (float)h0);
                xh[4 + j] = h1; xl[4 + j] = (bf16_t)(a1[j] - (float)h1);
            }
#pragma unroll
            for (int nt = 0; nt < 4; ++nt) {
                size_t wo = (size_t)(nt * 16 + l16) * 512 + ks * 32 + quad * 8;
                bf16x8 bh = *(const bf16x8*)(wh + wo);
                bf16x8 bl = *(const bf16x8*)(wl + wo);
                acc[nt] = mfma16(xh, bh, acc[nt]);
                acc[nt] = mfma16(xh, bl, acc[nt]);
                acc[nt] = mfma16(xl, bh, acc[nt]);
            }
        }
        unsigned base_h = (nT == 0) ? OFF_QH : OFF_KH;
        unsigned base_l = (nT == 0) ? OFF_QL : OFF_KL;
#pragma unroll
        for (int nt = 0; nt < 4; ++nt) {
            int gc = nt * 16 + l16;            // 0..63
#pragma unroll
            for (int r = 0; r < 4; ++r) {
                int gr = mt * 64 + w * 16 + quad * 4 + r;
                int b = gr >> 12, np = gr & 4095;
                float v = acc[nt][r];
                bf16_t h = (bf16_t)v;
                size_t o = ((size_t)(b * 4096 + np)) * 64 + gc;
                ws[base_h + o] = h;
                ws[base_l + o] = (bf16_t)(v - (float)h);
            }
        }
    } else {
        // V path: single bf16
        const bf16_t* wp = ws + OFF_WD + (size_t)(nT - 2) * 64 * 512;
#pragma unroll 4
        for (int ks = 0; ks < 16; ++ks) {
            f32x4 a0 = *(const f32x4*)(xrow + ks * 32 + quad * 8);
            f32x4 a1 = *(const f32x4*)(xrow + ks * 32 + quad * 8 + 4);
            bf16x8 xh;
#pragma unroll
            for (int j = 0; j < 4; ++j) {
                xh[j] = (bf16_t)a0[j];
                xh[4 + j] = (bf16_t)a1[j];
            }
#pragma unroll
            for (int nt = 0; nt < 4; ++nt) {
                bf16x8 bb = *(const bf16x8*)(wp + (size_t)(nt * 16 + l16) * 512 + ks * 32 + quad * 8);
                acc[nt] = mfma16(xh, bb, acc[nt]);
            }
        }
#pragma unroll
        for (int nt = 0; nt < 4; ++nt) {
            int gc = (nT - 2) * 64 + nt * 16 + l16;   // V channel 0..511
#pragma unroll
            for (int r = 0; r < 4; ++r) {
                int gr = mt * 64 + w * 16 + quad * 4 + r;
                int b = gr >> 12, np = gr & 4095;
                ws[OFF_VT + ((size_t)b * 512 + (size_t)gc) * 4096 + np] = (bf16_t)acc[nt][r];
            }
        }
    }
}

// --------------------------- K2: flash attention ----------------------------
// One workgroup = (batch b, 64-row Q tile). 4 waves: wave w computes S rows
// [16w,16w+16) and owns O/V columns [128w,128w+128). P round-trips via LDS.
__global__ __launch_bounds__(256, 1) void attn_kernel(const float* __restrict__ x,
                                                      const float* __restrict__ gamma_p,
                                                      const bf16_t* __restrict__ ws,
                                                      float* __restrict__ out) {
    int idx = blockIdx.x;
    int b = (idx >> 1) & 3;                    // batch<->XCD affinity heuristic
    int qt = (idx >> 3) * 2 + (idx & 1);
    int tid = threadIdx.x;
    int w = tid >> 6, lane = tid & 63, quad = lane >> 4, l16 = lane & 15;

    __shared__ __align__(16) bf16_t Ps[64][72];   // stride 72 -> bank spread
    __shared__ __align__(16) float alpha_s[64];
    __shared__ __align__(16) float ls[64];

    const bf16_t* Qh = ws + OFF_QH + (size_t)b * NN * 64;
    const bf16_t* Ql = ws + OFF_QL + (size_t)b * NN * 64;
    const bf16_t* Kh = ws + OFF_KH + (size_t)b * NN * 64;
    const bf16_t* Kl = ws + OFF_KL + (size_t)b * NN * 64;
    const bf16_t* Vt = ws + OFF_VT + (size_t)b * CC * NN;

    // Q fragments (rows qt*64 + w*16 + l16), held for the whole kernel
    const bf16_t* qbase_h = Qh + (size_t)(qt * 64 + w * 16 + l16) * 64 + quad * 8;
    const bf16_t* qbase_l = Ql + (size_t)(qt * 64 + w * 16 + l16) * 64 + quad * 8;
    bf16x8 qh[2], ql[2];
    qh[0] = *(const bf16x8*)(qbase_h);
    qh[1] = *(const bf16x8*)(qbase_h + 32);
    ql[0] = *(const bf16x8*)(qbase_l);
    ql[1] = *(const bf16x8*)(qbase_l + 32);

    f32x4 o[4][8];
#pragma unroll
    for (int rt = 0; rt < 4; ++rt)
#pragma unroll
        for (int ct = 0; ct < 8; ++ct) o[rt][ct] = (f32x4){0.f, 0.f, 0.f, 0.f};

    float m_run[4], l_run[4];
#pragma unroll
    for (int r = 0; r < 4; ++r) { m_run[r] = -INFINITY; l_run[r] = 0.f; }

    for (int kt = 0; kt < 64; ++kt) {
        // ---- S = Q K^T for this wave's 16 rows x 64 cols (hi/lo split) ----
        f32x4 s[4];
#pragma unroll
        for (int nt = 0; nt < 4; ++nt) {
            const bf16_t* krow_h = Kh + (size_t)(kt * 64 + nt * 16 + l16) * 64 + quad * 8;
            const bf16_t* krow_l = Kl + (size_t)(kt * 64 + nt * 16 + l16) * 64 + quad * 8;
            bf16x8 kh0 = *(const bf16x8*)(krow_h);
            bf16x8 kh1 = *(const bf16x8*)(krow_h + 32);
            bf16x8 kl0 = *(const bf16x8*)(krow_l);
            bf16x8 kl1 = *(const bf16x8*)(krow_l + 32);
            f32x4 a = (f32x4){0.f, 0.f, 0.f, 0.f};
            a = mfma16(qh[0], kh0, a);
            a = mfma16(qh[1], kh1, a);
            a = mfma16(qh[0], kl0, a);
            a = mfma16(qh[1], kl1, a);
            a = mfma16(ql[0], kh0, a);
            a = mfma16(ql[1], kh1, a);
            s[nt] = a;
        }

        // ---- online softmax over this wave's rows ----
        float mx[4];
#pragma unroll
        for (int r = 0; r < 4; ++r)
            mx[r] = fmaxf(fmaxf(s[0][r], s[1][r]), fmaxf(s[2][r], s[3][r]));
#pragma unroll
        for (int off = 1; off < 16; off <<= 1)
#pragma unroll
            for (int r = 0; r < 4; ++r) mx[r] = fmaxf(mx[r], __shfl_xor(mx[r], off));

        float alpha[4];
#pragma unroll
        for (int r = 0; r < 4; ++r) {
            float mn = fmaxf(m_run[r], mx[r]);
            alpha[r] = __expf(m_run[r] - mn);
            m_run[r] = mn;
        }

        float rs[4] = {0.f, 0.f, 0.f, 0.f};
#pragma unroll
        for (int nt = 0; nt < 4; ++nt)
#pragma unroll
            for (int r = 0; r < 4; ++r) {
                float p = __expf(s[nt][r] - m_run[r]);
                bf16_t pb = (bf16_t)p;
                Ps[w * 16 + quad * 4 + r][nt * 16 + l16] = pb;
                rs[r] += (float)pb;
            }
#pragma unroll
        for (int off = 1; off < 16; off <<= 1)
#pragma unroll
            for (int r = 0; r < 4; ++r) rs[r] += __shfl_xor(rs[r], off);
#pragma unroll
        for (int r = 0; r < 4; ++r) l_run[r] = l_run[r] * alpha[r] + rs[r];

        if (l16 == 0) {
#pragma unroll
            for (int r = 0; r < 4; ++r) alpha_s[w * 16 + quad * 4 + r] = alpha[r];
        }
        __syncthreads();

        // ---- rescale O by alpha (all 64 rows, this wave's 128 cols) ----
#pragma unroll
        for (int rt = 0; rt < 4; ++rt) {
            f32x4 av = *(const f32x4*)&alpha_s[rt * 16 + quad * 4];
#pragma unroll
            for (int ct = 0; ct < 8; ++ct) o[rt][ct] *= av;
        }

        // ---- O += P V : A-frags from LDS, B-frags from Vt (contiguous) ----
        bf16x8 pa[4][2];
#pragma unroll
        for (int rt = 0; rt < 4; ++rt) {
            pa[rt][0] = *(const bf16x8*)&Ps[rt * 16 + l16][quad * 8];
            pa[rt][1] = *(const bf16x8*)&Ps[rt * 16 + l16][32 + quad * 8];
        }
#pragma unroll
        for (int ct = 0; ct < 8; ++ct) {
            const bf16_t* vrow = Vt + (size_t)(w * 128 + ct * 16 + l16) * 4096 + kt * 64 + quad * 8;
            bf16x8 v0 = *(const bf16x8*)(vrow);
            bf16x8 v1 = *(const bf16x8*)(vrow + 32);
#pragma unroll
            for (int rt = 0; rt < 4; ++rt) {
                o[rt][ct] = mfma16(pa[rt][0], v0, o[rt][ct]);
                o[rt][ct] = mfma16(pa[rt][1], v1, o[rt][ct]);
            }
        }
        __syncthreads();
    }

    // ---- epilogue: out = gamma * O / l + x (fp32) ----
    if (l16 == 0) {
#pragma unroll
        for (int r = 0; r < 4; ++r) ls[w * 16 + quad * 4 + r] = l_run[r];
    }
    __syncthreads();

    float g = gamma_p[0];
#pragma unroll
    for (int rt = 0; rt < 4; ++rt) {
        f32x4 lv = *(const f32x4*)&ls[rt * 16 + quad * 4];
        f32x4 linv;
#pragma unroll
        for (int r = 0; r < 4; ++r) linv[r] = 1.0f / lv[r];
#pragma unroll
        for (int ct = 0; ct < 8; ++ct) {
#pragma unroll
            for (int r = 0; r < 4; ++r) {
                int np = qt * 64 + rt * 16 + quad * 4 + r;
                int c = w * 128 + ct * 16 + l16;
                size_t off = ((size_t)(b * 4096 + np)) * 512 + c;
                out[off] = g * (o[rt][ct][r] * linv[r]) + x[off];
            }
        }
    }
}

// ---------------------------------------------------------------------------
extern "C" void kernel_launch(void* const* d_in, const int* in_sizes, int n_in,
                              void* d_out, int out_size, void* d_ws, size_t ws_size,
                              hipStream_t stream) {
    const float* x     = (const float*)d_in[0];
    const float* Wb    = (const float*)d_in[1];
    const float* Wc    = (const float*)d_in[2];
    const float* Wd    = (const float*)d_in[3];
    const float* gamma = (const float*)d_in[4];
    bf16_t* ws = (bf16_t*)d_ws;
    float* out = (float*)d_out;

    prep_kernel<<<1280, 256, 0, stream>>>(Wb, Wc, Wd, ws);
    qkv_kernel<<<2560, 256, 0, stream>>>(x, ws);
    attn_kernel<<<256, 256, 0, stream>>>(x, gamma, ws, out);
}

// Round 3
// 587.144 us; speedup vs baseline: 1.0883x; 1.0883x over previous
//
#include <hip/hip_runtime.h>

// ---------------------------------------------------------------------------
// PAM: out = gamma * softmax((X Wb)(X Wc)^T) (X Wd) + X
// B=4, H=W=64 (N=4096), C=512, CR=64. Inputs/outputs fp32; MFMA in bf16 with
// hi/lo splitting for Q/K accuracy.
// ---------------------------------------------------------------------------

typedef __bf16 bf16_t;
typedef __bf16 bf16x8 __attribute__((ext_vector_type(8)));
typedef float f32x4 __attribute__((ext_vector_type(4)));

#define NN 4096
#define CC 512

// workspace layout, in bf16 elements (~59.5 MB)
#define OFF_QH 0u
#define OFF_QL 1048576u
#define OFF_KH 2097152u
#define OFF_KL 3145728u
#define OFF_VT 4194304u            // Vt[b][c][n], 4*512*4096
#define OFF_XH 12582912u           // X hi bf16, 4*4096*512
#define OFF_XL 20971520u           // X lo bf16
#define OFF_WBH 29360128u          // Wt_b hi [64][512]
#define OFF_WBL 29392896u
#define OFF_WCH 29425664u
#define OFF_WCL 29458432u
#define OFF_WD  29491200u          // Wt_d [512][512]

static __device__ __forceinline__ f32x4 mfma16(bf16x8 a, bf16x8 b, f32x4 c) {
    return __builtin_amdgcn_mfma_f32_16x16x32_bf16(a, b, c, 0, 0, 0);
}

// ------------------- K0: prep (X->bf16 hi/lo, W transpose) ------------------
__global__ __launch_bounds__(256) void prep_kernel(const float* __restrict__ x,
                                                   const float* __restrict__ Wb,
                                                   const float* __restrict__ Wc,
                                                   const float* __restrict__ Wd,
                                                   bf16_t* __restrict__ ws) {
    int idx = blockIdx.x * 256 + threadIdx.x;
    if (idx < 2097152) {                       // X: 8.39M el, 4 per thread
        f32x4 v = *(const f32x4*)(x + (size_t)idx * 4);
        bf16_t h[4], l[4];
#pragma unroll
        for (int j = 0; j < 4; ++j) {
            h[j] = (bf16_t)v[j];
            l[j] = (bf16_t)(v[j] - (float)h[j]);
        }
        *(ulong1*)(ws + OFF_XH + (size_t)idx * 4) = *(ulong1*)h;
        *(ulong1*)(ws + OFF_XL + (size_t)idx * 4) = *(ulong1*)l;
        return;
    }
    int j = idx - 2097152;
    if (j < 32768) {                           // Wb [512][64] -> hi/lo [64][512]
        int n = j >> 9, k = j & 511;
        float v = Wb[k * 64 + n];
        bf16_t h = (bf16_t)v;
        ws[OFF_WBH + j] = h;
        ws[OFF_WBL + j] = (bf16_t)(v - (float)h);
    } else if (j < 65536) {
        int j2 = j - 32768;
        int n = j2 >> 9, k = j2 & 511;
        float v = Wc[k * 64 + n];
        bf16_t h = (bf16_t)v;
        ws[OFF_WCH + j2] = h;
        ws[OFF_WCL + j2] = (bf16_t)(v - (float)h);
    } else if (j < 65536 + 262144) {           // Wd [512][512]
        int j2 = j - 65536;
        int n = j2 >> 9, k = j2 & 511;
        ws[OFF_WD + j2] = (bf16_t)Wd[k * 512 + n];
    }
}

// --------------------------- K1: fused QKV projection -----------------------
// Xbf[16384,512] (hi/lo) times W[512,640].
// nT=0 -> Q (hi/lo out), nT=1 -> K (hi/lo out), nT>=2 -> V stored Vt[b][c][n].
__global__ __launch_bounds__(256) void qkv_kernel(bf16_t* __restrict__ ws) {
    int nT = blockIdx.x % 10;
    int mt = blockIdx.x / 10;
    int tid = threadIdx.x;
    int w = tid >> 6, lane = tid & 63, quad = lane >> 4, l16 = lane & 15;

    size_t row = (size_t)(mt * 64 + w * 16 + l16) * 512;
    const bf16_t* xh_row = ws + OFF_XH + row;
    const bf16_t* xl_row = ws + OFF_XL + row;

    f32x4 acc[4];
#pragma unroll
    for (int nt = 0; nt < 4; ++nt) acc[nt] = (f32x4){0.f, 0.f, 0.f, 0.f};

    if (nT < 2) {
        // Q/K path: hi/lo on BOTH X and W -> near-fp32 projection
        const bf16_t* wh = ws + (nT == 0 ? OFF_WBH : OFF_WCH);
        const bf16_t* wl = ws + (nT == 0 ? OFF_WBL : OFF_WCL);
#pragma unroll 4
        for (int ks = 0; ks < 16; ++ks) {
            bf16x8 xh = *(const bf16x8*)(xh_row + ks * 32 + quad * 8);
            bf16x8 xl = *(const bf16x8*)(xl_row + ks * 32 + quad * 8);
#pragma unroll
            for (int nt = 0; nt < 4; ++nt) {
                size_t wo = (size_t)(nt * 16 + l16) * 512 + ks * 32 + quad * 8;
                bf16x8 bh = *(const bf16x8*)(wh + wo);
                bf16x8 bl = *(const bf16x8*)(wl + wo);
                acc[nt] = mfma16(xh, bh, acc[nt]);
                acc[nt] = mfma16(xh, bl, acc[nt]);
                acc[nt] = mfma16(xl, bh, acc[nt]);
            }
        }
        unsigned base_h = (nT == 0) ? OFF_QH : OFF_KH;
        unsigned base_l = (nT == 0) ? OFF_QL : OFF_KL;
#pragma unroll
        for (int nt = 0; nt < 4; ++nt) {
            int gc = nt * 16 + l16;            // 0..63
#pragma unroll
            for (int r = 0; r < 4; ++r) {
                int gr = mt * 64 + w * 16 + quad * 4 + r;
                int b = gr >> 12, np = gr & 4095;
                float v = acc[nt][r];
                bf16_t h = (bf16_t)v;
                size_t o = ((size_t)(b * 4096 + np)) * 64 + gc;
                ws[base_h + o] = h;
                ws[base_l + o] = (bf16_t)(v - (float)h);
            }
        }
    } else {
        // V path: single bf16
        const bf16_t* wp = ws + OFF_WD + (size_t)(nT - 2) * 64 * 512;
#pragma unroll 4
        for (int ks = 0; ks < 16; ++ks) {
            bf16x8 xh = *(const bf16x8*)(xh_row + ks * 32 + quad * 8);
#pragma unroll
            for (int nt = 0; nt < 4; ++nt) {
                bf16x8 bb = *(const bf16x8*)(wp + (size_t)(nt * 16 + l16) * 512 + ks * 32 + quad * 8);
                acc[nt] = mfma16(xh, bb, acc[nt]);
            }
        }
#pragma unroll
        for (int nt = 0; nt < 4; ++nt) {
            int gc = (nT - 2) * 64 + nt * 16 + l16;   // V channel 0..511
#pragma unroll
            for (int r = 0; r < 4; ++r) {
                int gr = mt * 64 + w * 16 + quad * 4 + r;
                int b = gr >> 12, np = gr & 4095;
                ws[OFF_VT + ((size_t)b * 512 + (size_t)gc) * 4096 + np] = (bf16_t)acc[nt][r];
            }
        }
    }
}

// --------------------------- K2: flash attention ----------------------------
// One workgroup = (batch b, 32-row Q tile); grid 512 -> 2 blocks/CU.
// Wave w: S strip [32 rows][cols 16w..16w+16), owns O/V columns [128w,128w+128).
// alpha/m/l per-row state lives in registers (O rows == S rows, same lanes);
// only strip max/sum cross waves via LDS.
__global__ __launch_bounds__(256) void attn_kernel(const float* __restrict__ x,
                                                   const float* __restrict__ gamma_p,
                                                   const bf16_t* __restrict__ ws,
                                                   float* __restrict__ out) {
    int idx = blockIdx.x;
    int b = (idx >> 1) & 3;                    // XCD pair <-> batch affinity
    int qt = ((idx >> 3) << 1) | (idx & 1);    // 0..127
    int tid = threadIdx.x;
    int w = tid >> 6, lane = tid & 63, quad = lane >> 4, l16 = lane & 15;

    __shared__ __align__(16) bf16_t Ps[32][72];
    __shared__ __align__(16) float pmax[32][4];
    __shared__ __align__(16) float psum[32][4];

    const bf16_t* Qh = ws + OFF_QH + (size_t)b * NN * 64;
    const bf16_t* Ql = ws + OFF_QL + (size_t)b * NN * 64;
    const bf16_t* Kh = ws + OFF_KH + (size_t)b * NN * 64;
    const bf16_t* Kl = ws + OFF_KL + (size_t)b * NN * 64;
    const bf16_t* Vt = ws + OFF_VT + (size_t)b * CC * NN;

    // Q fragments: rows qt*32 + rt*16 + l16, held for the whole kernel
    bf16x8 qh[2][2], ql[2][2];
#pragma unroll
    for (int rt = 0; rt < 2; ++rt) {
        size_t qo = (size_t)(qt * 32 + rt * 16 + l16) * 64 + quad * 8;
        qh[rt][0] = *(const bf16x8*)(Qh + qo);
        qh[rt][1] = *(const bf16x8*)(Qh + qo + 32);
        ql[rt][0] = *(const bf16x8*)(Ql + qo);
        ql[rt][1] = *(const bf16x8*)(Ql + qo + 32);
    }

    f32x4 o[2][8];
#pragma unroll
    for (int rt = 0; rt < 2; ++rt)
#pragma unroll
        for (int ct = 0; ct < 8; ++ct) o[rt][ct] = (f32x4){0.f, 0.f, 0.f, 0.f};

    float m_run[2][4], l_run[2][4];
#pragma unroll
    for (int rt = 0; rt < 2; ++rt)
#pragma unroll
        for (int r = 0; r < 4; ++r) { m_run[rt][r] = -INFINITY; l_run[rt][r] = 0.f; }

    for (int kt = 0; kt < 64; ++kt) {
        // ---- S strip: this wave's 16 cols over 32 rows (hi/lo split) ----
        size_t ko = (size_t)(kt * 64 + w * 16 + l16) * 64 + quad * 8;
        bf16x8 kh0 = *(const bf16x8*)(Kh + ko);
        bf16x8 kh1 = *(const bf16x8*)(Kh + ko + 32);
        bf16x8 kl0 = *(const bf16x8*)(Kl + ko);
        bf16x8 kl1 = *(const bf16x8*)(Kl + ko + 32);
        f32x4 s[2];
#pragma unroll
        for (int rt = 0; rt < 2; ++rt) {
            f32x4 a = (f32x4){0.f, 0.f, 0.f, 0.f};
            a = mfma16(qh[rt][0], kh0, a);
            a = mfma16(qh[rt][1], kh1, a);
            a = mfma16(qh[rt][0], kl0, a);
            a = mfma16(qh[rt][1], kl1, a);
            a = mfma16(ql[rt][0], kh0, a);
            a = mfma16(ql[rt][1], kh1, a);
            s[rt] = a;
        }

        // ---- strip row-max (over l16) -> LDS ----
        float mx[2][4];
#pragma unroll
        for (int rt = 0; rt < 2; ++rt)
#pragma unroll
            for (int r = 0; r < 4; ++r) mx[rt][r] = s[rt][r];
#pragma unroll
        for (int off = 1; off < 16; off <<= 1)
#pragma unroll
            for (int rt = 0; rt < 2; ++rt)
#pragma unroll
                for (int r = 0; r < 4; ++r) mx[rt][r] = fmaxf(mx[rt][r], __shfl_xor(mx[rt][r], off));
        if (l16 == 0) {
#pragma unroll
            for (int rt = 0; rt < 2; ++rt)
#pragma unroll
                for (int r = 0; r < 4; ++r) pmax[rt * 16 + quad * 4 + r][w] = mx[rt][r];
        }
        __syncthreads();

        // ---- combine maxes; exp; write P; strip row-sum -> LDS ----
        float alpha[2][4], rs[2][4];
#pragma unroll
        for (int rt = 0; rt < 2; ++rt)
#pragma unroll
            for (int r = 0; r < 4; ++r) {
                int row = rt * 16 + quad * 4 + r;
                f32x4 pm = *(const f32x4*)pmax[row];
                float mn = fmaxf(fmaxf(pm[0], pm[1]), fmaxf(pm[2], pm[3]));
                mn = fmaxf(m_run[rt][r], mn);
                alpha[rt][r] = __expf(m_run[rt][r] - mn);
                m_run[rt][r] = mn;
                float p = __expf(s[rt][r] - mn);
                bf16_t pb = (bf16_t)p;
                Ps[row][w * 16 + l16] = pb;
                rs[rt][r] = (float)pb;
            }
#pragma unroll
        for (int off = 1; off < 16; off <<= 1)
#pragma unroll
            for (int rt = 0; rt < 2; ++rt)
#pragma unroll
                for (int r = 0; r < 4; ++r) rs[rt][r] += __shfl_xor(rs[rt][r], off);
        if (l16 == 0) {
#pragma unroll
            for (int rt = 0; rt < 2; ++rt)
#pragma unroll
                for (int r = 0; r < 4; ++r) psum[rt * 16 + quad * 4 + r][w] = rs[rt][r];
        }
        __syncthreads();

        // ---- fold strip sums; rescale O; O += P V ----
#pragma unroll
        for (int rt = 0; rt < 2; ++rt) {
            f32x4 av;
#pragma unroll
            for (int r = 0; r < 4; ++r) {
                f32x4 ps4 = *(const f32x4*)psum[rt * 16 + quad * 4 + r];
                l_run[rt][r] = l_run[rt][r] * alpha[rt][r] + (ps4[0] + ps4[1] + ps4[2] + ps4[3]);
                av[r] = alpha[rt][r];
            }
#pragma unroll
            for (int ct = 0; ct < 8; ++ct) o[rt][ct] *= av;
        }

        bf16x8 pa[2][2];
#pragma unroll
        for (int rt = 0; rt < 2; ++rt) {
            pa[rt][0] = *(const bf16x8*)&Ps[rt * 16 + l16][quad * 8];
            pa[rt][1] = *(const bf16x8*)&Ps[rt * 16 + l16][32 + quad * 8];
        }
#pragma unroll
        for (int ct = 0; ct < 8; ++ct) {
            const bf16_t* vrow = Vt + (size_t)(w * 128 + ct * 16 + l16) * 4096 + kt * 64 + quad * 8;
            bf16x8 v0 = *(const bf16x8*)(vrow);
            bf16x8 v1 = *(const bf16x8*)(vrow + 32);
#pragma unroll
            for (int rt = 0; rt < 2; ++rt) {
                o[rt][ct] = mfma16(pa[rt][0], v0, o[rt][ct]);
                o[rt][ct] = mfma16(pa[rt][1], v1, o[rt][ct]);
            }
        }
        // no barrier here: next Ps/pmax writes are fenced by the two barriers
        // above before they can be reached again.
    }

    // ---- epilogue: out = gamma * O / l + x (fp32, all state in-register) ----
    float g = gamma_p[0];
#pragma unroll
    for (int rt = 0; rt < 2; ++rt) {
        f32x4 linv;
#pragma unroll
        for (int r = 0; r < 4; ++r) linv[r] = 1.0f / l_run[rt][r];
#pragma unroll
        for (int ct = 0; ct < 8; ++ct) {
#pragma unroll
            for (int r = 0; r < 4; ++r) {
                int np = qt * 32 + rt * 16 + quad * 4 + r;
                int c = w * 128 + ct * 16 + l16;
                size_t off = ((size_t)(b * 4096 + np)) * 512 + c;
                out[off] = g * (o[rt][ct][r] * linv[r]) + x[off];
            }
        }
    }
}

// ---------------------------------------------------------------------------
extern "C" void kernel_launch(void* const* d_in, const int* in_sizes, int n_in,
                              void* d_out, int out_size, void* d_ws, size_t ws_size,
                              hipStream_t stream) {
    const float* x     = (const float*)d_in[0];
    const float* Wb    = (const float*)d_in[1];
    const float* Wc    = (const float*)d_in[2];
    const float* Wd    = (const float*)d_in[3];
    const float* gamma = (const float*)d_in[4];
    bf16_t* ws = (bf16_t*)d_ws;
    float* out = (float*)d_out;

    prep_kernel<<<9472, 256, 0, stream>>>(x, Wb, Wc, Wd, ws);
    qkv_kernel<<<2560, 256, 0, stream>>>(ws);
    attn_kernel<<<512, 256, 0, stream>>>(x, gamma, ws, out);
}

// Round 4
// 586.373 us; speedup vs baseline: 1.0897x; 1.0013x over previous
//
#include <hip/hip_runtime.h>

// ---------------------------------------------------------------------------
// PAM: out = gamma * softmax((X Wb)(X Wc)^T) (X Wd) + X
// B=4, H=W=64 (N=4096), C=512, CR=64. Inputs/outputs fp32; MFMA in bf16 with
// hi/lo splitting for Q/K accuracy. Vt rows padded (4160) to break 8KB
// power-of-2 L2 channel aliasing.
// ---------------------------------------------------------------------------

typedef __bf16 bf16_t;
typedef __bf16 bf16x8 __attribute__((ext_vector_type(8)));
typedef float f32x4 __attribute__((ext_vector_type(4)));
typedef unsigned long long u64;

#define NN 4096
#define CC 512
#define VSTRIDE 4160u              // padded Vt row stride (elements)

// workspace layout, in bf16 elements (~59.8 MB)
#define OFF_QH 0u
#define OFF_QL 1048576u
#define OFF_KH 2097152u
#define OFF_KL 3145728u
#define OFF_VT 4194304u            // Vt[b][c][VSTRIDE], 4*512*4160
#define OFF_XH 12713984u           // X hi bf16, 4*4096*512
#define OFF_XL 21102592u           // X lo bf16
#define OFF_WBH 29491200u          // Wt_b hi [64][512]
#define OFF_WBL 29523968u
#define OFF_WCH 29556736u
#define OFF_WCL 29589504u
#define OFF_WD  29622272u          // Wt_d [512][512]

static __device__ __forceinline__ f32x4 mfma16(bf16x8 a, bf16x8 b, f32x4 c) {
    return __builtin_amdgcn_mfma_f32_16x16x32_bf16(a, b, c, 0, 0, 0);
}

// ------------------- K0: prep (X->bf16 hi/lo, W transpose) ------------------
__global__ __launch_bounds__(256) void prep_kernel(const float* __restrict__ x,
                                                   const float* __restrict__ Wb,
                                                   const float* __restrict__ Wc,
                                                   const float* __restrict__ Wd,
                                                   bf16_t* __restrict__ ws) {
    int idx = blockIdx.x * 256 + threadIdx.x;
    if (idx < 2097152) {                       // X: 8.39M el, 4 per thread
        f32x4 v = *(const f32x4*)(x + (size_t)idx * 4);
        bf16_t h[4], l[4];
#pragma unroll
        for (int j = 0; j < 4; ++j) {
            h[j] = (bf16_t)v[j];
            l[j] = (bf16_t)(v[j] - (float)h[j]);
        }
        *(u64*)(ws + OFF_XH + (size_t)idx * 4) = *(u64*)h;
        *(u64*)(ws + OFF_XL + (size_t)idx * 4) = *(u64*)l;
        return;
    }
    int j = idx - 2097152;
    if (j < 32768) {                           // Wb [512][64] -> hi/lo [64][512]
        int n = j >> 9, k = j & 511;
        float v = Wb[k * 64 + n];
        bf16_t h = (bf16_t)v;
        ws[OFF_WBH + j] = h;
        ws[OFF_WBL + j] = (bf16_t)(v - (float)h);
    } else if (j < 65536) {
        int j2 = j - 32768;
        int n = j2 >> 9, k = j2 & 511;
        float v = Wc[k * 64 + n];
        bf16_t h = (bf16_t)v;
        ws[OFF_WCH + j2] = h;
        ws[OFF_WCL + j2] = (bf16_t)(v - (float)h);
    } else if (j < 65536 + 262144) {           // Wd [512][512]
        int j2 = j - 65536;
        int n = j2 >> 9, k = j2 & 511;
        ws[OFF_WD + j2] = (bf16_t)Wd[k * 512 + n];
    }
}

// --------------------------- K1: fused QKV projection -----------------------
// Xbf[16384,512] (hi/lo) times W[512,640].
// nT=0 -> Q (hi/lo out), nT=1 -> K (hi/lo out), nT>=2 -> V stored Vt[b][c][n]
// (transposed via LDS so global stores are 128B-coalesced, padded stride).
__global__ __launch_bounds__(256) void qkv_kernel(bf16_t* __restrict__ ws) {
    int nT = blockIdx.x % 10;
    int mt = blockIdx.x / 10;
    int tid = threadIdx.x;
    int w = tid >> 6, lane = tid & 63, quad = lane >> 4, l16 = lane & 15;

    __shared__ __align__(16) bf16_t Vs[64][72];   // [channel][position]

    size_t row = (size_t)(mt * 64 + w * 16 + l16) * 512;
    const bf16_t* xh_row = ws + OFF_XH + row;
    const bf16_t* xl_row = ws + OFF_XL + row;

    f32x4 acc[4];
#pragma unroll
    for (int nt = 0; nt < 4; ++nt) acc[nt] = (f32x4){0.f, 0.f, 0.f, 0.f};

    if (nT < 2) {
        // Q/K path: hi/lo on BOTH X and W -> near-fp32 projection
        const bf16_t* wh = ws + (nT == 0 ? OFF_WBH : OFF_WCH);
        const bf16_t* wl = ws + (nT == 0 ? OFF_WBL : OFF_WCL);
#pragma unroll 4
        for (int ks = 0; ks < 16; ++ks) {
            bf16x8 xh = *(const bf16x8*)(xh_row + ks * 32 + quad * 8);
            bf16x8 xl = *(const bf16x8*)(xl_row + ks * 32 + quad * 8);
#pragma unroll
            for (int nt = 0; nt < 4; ++nt) {
                size_t wo = (size_t)(nt * 16 + l16) * 512 + ks * 32 + quad * 8;
                bf16x8 bh = *(const bf16x8*)(wh + wo);
                bf16x8 bl = *(const bf16x8*)(wl + wo);
                acc[nt] = mfma16(xh, bh, acc[nt]);
                acc[nt] = mfma16(xh, bl, acc[nt]);
                acc[nt] = mfma16(xl, bh, acc[nt]);
            }
        }
        unsigned base_h = (nT == 0) ? OFF_QH : OFF_KH;
        unsigned base_l = (nT == 0) ? OFF_QL : OFF_KL;
#pragma unroll
        for (int nt = 0; nt < 4; ++nt) {
            int gc = nt * 16 + l16;            // 0..63
#pragma unroll
            for (int r = 0; r < 4; ++r) {
                int gr = mt * 64 + w * 16 + quad * 4 + r;
                int b = gr >> 12, np = gr & 4095;
                float v = acc[nt][r];
                bf16_t h = (bf16_t)v;
                size_t o = ((size_t)(b * 4096 + np)) * 64 + gc;
                ws[base_h + o] = h;
                ws[base_l + o] = (bf16_t)(v - (float)h);
            }
        }
    } else {
        // V path: single bf16, epilogue transposed via LDS
        const bf16_t* wp = ws + OFF_WD + (size_t)(nT - 2) * 64 * 512;
#pragma unroll 4
        for (int ks = 0; ks < 16; ++ks) {
            bf16x8 xh = *(const bf16x8*)(xh_row + ks * 32 + quad * 8);
#pragma unroll
            for (int nt = 0; nt < 4; ++nt) {
                bf16x8 bb = *(const bf16x8*)(wp + (size_t)(nt * 16 + l16) * 512 + ks * 32 + quad * 8);
                acc[nt] = mfma16(xh, bb, acc[nt]);
            }
        }
        // acc[nt][r] = V[pos = mt*64 + w*16 + quad*4 + r][ch = nt*16 + l16]
#pragma unroll
        for (int nt = 0; nt < 4; ++nt) {
            bf16_t pk[4];
#pragma unroll
            for (int r = 0; r < 4; ++r) pk[r] = (bf16_t)acc[nt][r];
            *(u64*)&Vs[nt * 16 + l16][w * 16 + quad * 4] = *(u64*)pk;
        }
        __syncthreads();
        // cooperative coalesced store: thread -> (channel, 16-position chunk)
        int gr0 = mt * 64;
        int bb = gr0 >> 12, np0 = gr0 & 4095;
        int ch = tid >> 2, seg = tid & 3;
        f32x4 d0 = *(const f32x4*)&Vs[ch][seg * 16];
        f32x4 d1 = *(const f32x4*)&Vs[ch][seg * 16 + 8];
        bf16_t* dst = ws + OFF_VT +
            ((size_t)bb * 512 + (size_t)((nT - 2) * 64 + ch)) * VSTRIDE + np0 + seg * 16;
        *(f32x4*)(dst) = d0;
        *(f32x4*)(dst + 8) = d1;
    }
}

// --------------------------- K2: flash attention ----------------------------
// One workgroup = (batch b, 32-row Q tile); grid 512 -> 2 blocks/CU.
// Wave w: S strip [32 rows][cols 16w..16w+16), owns O/V columns [128w,128w+128).
// alpha/m/l per-row state lives in registers; strip max/sum cross via LDS.
__global__ __launch_bounds__(256) void attn_kernel(const float* __restrict__ x,
                                                   const float* __restrict__ gamma_p,
                                                   const bf16_t* __restrict__ ws,
                                                   float* __restrict__ out) {
    int idx = blockIdx.x;
    int b = (idx >> 1) & 3;                    // XCD <-> batch affinity
    int qt = ((idx >> 3) << 1) | (idx & 1);    // 0..127
    int tid = threadIdx.x;
    int w = tid >> 6, lane = tid & 63, quad = lane >> 4, l16 = lane & 15;

    __shared__ __align__(16) bf16_t Ps[32][72];
    __shared__ __align__(16) float pmax[32][4];
    __shared__ __align__(16) float psum[32][4];

    const bf16_t* Qh = ws + OFF_QH + (size_t)b * NN * 64;
    const bf16_t* Ql = ws + OFF_QL + (size_t)b * NN * 64;
    const bf16_t* Kh = ws + OFF_KH + (size_t)b * NN * 64;
    const bf16_t* Kl = ws + OFF_KL + (size_t)b * NN * 64;
    const bf16_t* Vt = ws + OFF_VT + (size_t)b * CC * VSTRIDE;

    // Q fragments: rows qt*32 + rt*16 + l16, held for the whole kernel
    bf16x8 qh[2][2], ql[2][2];
#pragma unroll
    for (int rt = 0; rt < 2; ++rt) {
        size_t qo = (size_t)(qt * 32 + rt * 16 + l16) * 64 + quad * 8;
        qh[rt][0] = *(const bf16x8*)(Qh + qo);
        qh[rt][1] = *(const bf16x8*)(Qh + qo + 32);
        ql[rt][0] = *(const bf16x8*)(Ql + qo);
        ql[rt][1] = *(const bf16x8*)(Ql + qo + 32);
    }

    f32x4 o[2][8];
#pragma unroll
    for (int rt = 0; rt < 2; ++rt)
#pragma unroll
        for (int ct = 0; ct < 8; ++ct) o[rt][ct] = (f32x4){0.f, 0.f, 0.f, 0.f};

    float m_run[2][4], l_run[2][4];
#pragma unroll
    for (int rt = 0; rt < 2; ++rt)
#pragma unroll
        for (int r = 0; r < 4; ++r) { m_run[rt][r] = -INFINITY; l_run[rt][r] = 0.f; }

    for (int kt = 0; kt < 64; ++kt) {
        // ---- S strip: this wave's 16 cols over 32 rows (hi/lo split) ----
        size_t ko = (size_t)(kt * 64 + w * 16 + l16) * 64 + quad * 8;
        bf16x8 kh0 = *(const bf16x8*)(Kh + ko);
        bf16x8 kh1 = *(const bf16x8*)(Kh + ko + 32);
        bf16x8 kl0 = *(const bf16x8*)(Kl + ko);
        bf16x8 kl1 = *(const bf16x8*)(Kl + ko + 32);
        f32x4 s[2];
#pragma unroll
        for (int rt = 0; rt < 2; ++rt) {
            f32x4 a = (f32x4){0.f, 0.f, 0.f, 0.f};
            a = mfma16(qh[rt][0], kh0, a);
            a = mfma16(qh[rt][1], kh1, a);
            a = mfma16(qh[rt][0], kl0, a);
            a = mfma16(qh[rt][1], kl1, a);
            a = mfma16(ql[rt][0], kh0, a);
            a = mfma16(ql[rt][1], kh1, a);
            s[rt] = a;
        }

        // ---- strip row-max (over l16) -> LDS ----
        float mx[2][4];
#pragma unroll
        for (int rt = 0; rt < 2; ++rt)
#pragma unroll
            for (int r = 0; r < 4; ++r) mx[rt][r] = s[rt][r];
#pragma unroll
        for (int off = 1; off < 16; off <<= 1)
#pragma unroll
            for (int rt = 0; rt < 2; ++rt)
#pragma unroll
                for (int r = 0; r < 4; ++r) mx[rt][r] = fmaxf(mx[rt][r], __shfl_xor(mx[rt][r], off));
        if (l16 == 0) {
#pragma unroll
            for (int rt = 0; rt < 2; ++rt)
#pragma unroll
                for (int r = 0; r < 4; ++r) pmax[rt * 16 + quad * 4 + r][w] = mx[rt][r];
        }
        __syncthreads();

        // ---- combine maxes; exp; write P; strip row-sum -> LDS ----
        float alpha[2][4], rs[2][4];
#pragma unroll
        for (int rt = 0; rt < 2; ++rt)
#pragma unroll
            for (int r = 0; r < 4; ++r) {
                int row = rt * 16 + quad * 4 + r;
                f32x4 pm = *(const f32x4*)pmax[row];
                float mn = fmaxf(fmaxf(pm[0], pm[1]), fmaxf(pm[2], pm[3]));
                mn = fmaxf(m_run[rt][r], mn);
                alpha[rt][r] = __expf(m_run[rt][r] - mn);
                m_run[rt][r] = mn;
                float p = __expf(s[rt][r] - mn);
                bf16_t pb = (bf16_t)p;
                Ps[row][w * 16 + l16] = pb;
                rs[rt][r] = (float)pb;
            }
#pragma unroll
        for (int off = 1; off < 16; off <<= 1)
#pragma unroll
            for (int rt = 0; rt < 2; ++rt)
#pragma unroll
                for (int r = 0; r < 4; ++r) rs[rt][r] += __shfl_xor(rs[rt][r], off);
        if (l16 == 0) {
#pragma unroll
            for (int rt = 0; rt < 2; ++rt)
#pragma unroll
                for (int r = 0; r < 4; ++r) psum[rt * 16 + quad * 4 + r][w] = rs[rt][r];
        }
        __syncthreads();

        // ---- fold strip sums; rescale O; O += P V ----
#pragma unroll
        for (int rt = 0; rt < 2; ++rt) {
            f32x4 av;
#pragma unroll
            for (int r = 0; r < 4; ++r) {
                f32x4 ps4 = *(const f32x4*)psum[rt * 16 + quad * 4 + r];
                l_run[rt][r] = l_run[rt][r] * alpha[rt][r] + (ps4[0] + ps4[1] + ps4[2] + ps4[3]);
                av[r] = alpha[rt][r];
            }
#pragma unroll
            for (int ct = 0; ct < 8; ++ct) o[rt][ct] *= av;
        }

        bf16x8 pa[2][2];
#pragma unroll
        for (int rt = 0; rt < 2; ++rt) {
            pa[rt][0] = *(const bf16x8*)&Ps[rt * 16 + l16][quad * 8];
            pa[rt][1] = *(const bf16x8*)&Ps[rt * 16 + l16][32 + quad * 8];
        }
#pragma unroll
        for (int ct = 0; ct < 8; ++ct) {
            const bf16_t* vrow = Vt + (size_t)(w * 128 + ct * 16 + l16) * VSTRIDE + kt * 64 + quad * 8;
            bf16x8 v0 = *(const bf16x8*)(vrow);
            bf16x8 v1 = *(const bf16x8*)(vrow + 32);
#pragma unroll
            for (int rt = 0; rt < 2; ++rt) {
                o[rt][ct] = mfma16(pa[rt][0], v0, o[rt][ct]);
                o[rt][ct] = mfma16(pa[rt][1], v1, o[rt][ct]);
            }
        }
        // no barrier: next Ps/pmax writes are fenced by the two barriers above
    }

    // ---- epilogue: out = gamma * O / l + x (fp32, state in-register) ----
    float g = gamma_p[0];
#pragma unroll
    for (int rt = 0; rt < 2; ++rt) {
        f32x4 linv;
#pragma unroll
        for (int r = 0; r < 4; ++r) linv[r] = 1.0f / l_run[rt][r];
#pragma unroll
        for (int ct = 0; ct < 8; ++ct) {
#pragma unroll
            for (int r = 0; r < 4; ++r) {
                int np = qt * 32 + rt * 16 + quad * 4 + r;
                int c = w * 128 + ct * 16 + l16;
                size_t off = ((size_t)(b * 4096 + np)) * 512 + c;
                out[off] = g * (o[rt][ct][r] * linv[r]) + x[off];
            }
        }
    }
}

// ---------------------------------------------------------------------------
extern "C" void kernel_launch(void* const* d_in, const int* in_sizes, int n_in,
                              void* d_out, int out_size, void* d_ws, size_t ws_size,
                              hipStream_t stream) {
    const float* x     = (const float*)d_in[0];
    const float* Wb    = (const float*)d_in[1];
    const float* Wc    = (const float*)d_in[2];
    const float* Wd    = (const float*)d_in[3];
    const float* gamma = (const float*)d_in[4];
    bf16_t* ws = (bf16_t*)d_ws;
    float* out = (float*)d_out;

    prep_kernel<<<9472, 256, 0, stream>>>(x, Wb, Wc, Wd, ws);
    qkv_kernel<<<2560, 256, 0, stream>>>(ws);
    attn_kernel<<<512, 256, 0, stream>>>(x, gamma, ws, out);
}